// Round 1
// baseline (680.493 us; speedup 1.0000x reference)
//
#include <hip/hip_runtime.h>
#include <math.h>

#define SCALE 0.35355339059327373f  // 1/sqrt(8)

// workspace float offsets
#define OFF_STATS 0              // [0..63] bn1 sum, [64..127] bn1 sq, [128..191] bn2 sum,
                                 // [192..255] bn2 sq, [256..263] bnc sum, [264..271] bnc sq
#define OFF_Q   512
#define OFF_K   (OFF_Q + 401408)
#define OFF_V   (OFF_K + 401408)
#define OFF_M   (OFF_V + 401408)
#define OFF_R   (OFF_M + 50176)
#define OFF_CTX (OFF_R + 50176)
#define OFF_YO  (OFF_CTX + 401408)
#define OFF_H1  (OFF_YO + 401408)
#define OFF_G1  (OFF_H1 + 401408)
#define OFF_H2  (OFF_G1 + 401408)

__device__ __forceinline__ float gelu_f(float v) {
    return 0.5f * v * (1.0f + erff(v * 0.70710678118654752f));
}

// ---------------------------------------------------------------------------
// LN(x), LN(y) + fused QKV projections (q scaled by 1/sqrt(hd) at write)
// grid (14 chunks of 56 tokens, 8 batches), 256 threads
// ---------------------------------------------------------------------------
__global__ __launch_bounds__(256) void k_qkv(
    const float* __restrict__ x, const float* __restrict__ y,
    const float* __restrict__ lnxw, const float* __restrict__ lnxb,
    const float* __restrict__ lnyw, const float* __restrict__ lnyb,
    const float* __restrict__ wr, const float* __restrict__ br,
    const float* __restrict__ wsw, const float* __restrict__ bs,
    float* __restrict__ ws)
{
    __shared__ float sx[64][56];
    __shared__ float sy[64][56];
    __shared__ float pred[4][56];
    __shared__ float predq[4][56];
    __shared__ float mean_s[56], inv_s[56];
    const int tid = threadIdx.x;
    const int chunk = blockIdx.x, b = blockIdx.y;
    const int n0 = chunk * 56;

    for (int idx = tid; idx < 64 * 56; idx += 256) {
        int c = idx / 56, t = idx % 56;
        sx[c][t] = x[(b * 64 + c) * 784 + n0 + t];
        sy[c][t] = y[(b * 64 + c) * 784 + n0 + t];
    }
    __syncthreads();

    const int t = tid % 56, g = tid / 56;  // g==4 -> idle lanes (tid>=224)
    for (int which = 0; which < 2; ++which) {
        float (*sm)[56] = which ? sy : sx;
        const float* w  = which ? lnyw : lnxw;
        const float* bb = which ? lnyb : lnxb;
        if (g < 4) {
            float s = 0.f, q = 0.f;
            for (int c = g * 16; c < g * 16 + 16; ++c) { float v = sm[c][t]; s += v; q += v * v; }
            pred[g][t] = s; predq[g][t] = q;
        }
        __syncthreads();
        if (g == 0) {
            float s = pred[0][t] + pred[1][t] + pred[2][t] + pred[3][t];
            float q = predq[0][t] + predq[1][t] + predq[2][t] + predq[3][t];
            float m = s * (1.0f / 64.0f);
            float var = q * (1.0f / 64.0f) - m * m;
            mean_s[t] = m; inv_s[t] = rsqrtf(var + 1e-5f);
        }
        __syncthreads();
        if (g < 4) {
            float m = mean_s[t], iv = inv_s[t];
            for (int c = g * 16; c < g * 16 + 16; ++c)
                sm[c][t] = (sm[c][t] - m) * iv * w[c] + bb[c];
        }
        __syncthreads();
    }

    float* qout = ws + OFF_Q;
    float* kout = ws + OFF_K;
    float* vout = ws + OFF_V;
    for (int idx = tid; idx < 56 * 192; idx += 256) {
        int tt = idx % 56, o = idx / 56;
        float acc = br[o] + bs[o];
        const float* wro = wr + o * 64;
        const float* wso = wsw + o * 64;
        for (int c = 0; c < 64; ++c) acc += sx[c][tt] * wro[c] + sy[c][tt] * wso[c];
        int s = o >> 6, h = (o >> 3) & 7, d = o & 7;
        int n = n0 + tt;
        float* dst = (s == 0) ? qout : (s == 1 ? kout : vout);
        if (s == 0) acc *= SCALE;
        dst[((b * 8 + h) * 784 + n) * 8 + d] = acc;
    }
}

// ---------------------------------------------------------------------------
// flash pass: per-row softmax stats (M, R=1/L) and ctx = softmax(qk^T) v
// grid (13 row-chunks of 64, 64 bh), 256 threads: lane=row, wave=m-partition
// ---------------------------------------------------------------------------
__global__ __launch_bounds__(256) void k_flash(float* __restrict__ ws)
{
    __shared__ float sK[784 * 8];
    __shared__ float sV[784 * 8];
    __shared__ float rmax[4][64];
    __shared__ float rsum[4][64];
    __shared__ float rpv[4][64][8];
    const int tid = threadIdx.x;
    const int chunk = blockIdx.x;   // 0..12
    const int bh = blockIdx.y;      // 0..63
    const float* q = ws + OFF_Q + bh * 784 * 8;
    const float* k = ws + OFF_K + bh * 784 * 8;
    const float* v = ws + OFF_V + bh * 784 * 8;
    for (int idx = tid; idx < 6272; idx += 256) { sK[idx] = k[idx]; sV[idx] = v[idx]; }
    __syncthreads();

    const int row = tid & 63, part = tid >> 6;
    const int n = chunk * 64 + row;
    const bool valid = n < 784;
    float qr[8];
    if (valid) {
        const float4* q4 = (const float4*)(q + n * 8);
        float4 a = q4[0], bq = q4[1];
        qr[0] = a.x; qr[1] = a.y; qr[2] = a.z; qr[3] = a.w;
        qr[4] = bq.x; qr[5] = bq.y; qr[6] = bq.z; qr[7] = bq.w;
    } else {
        for (int d = 0; d < 8; ++d) qr[d] = 0.f;
    }

    float mx = -1e30f;
    for (int i = 0; i < 196; ++i) {
        int m = part * 196 + i;
        const float4* k4 = (const float4*)(sK + m * 8);
        float4 ka = k4[0], kb = k4[1];
        float dot = qr[0]*ka.x + qr[1]*ka.y + qr[2]*ka.z + qr[3]*ka.w
                  + qr[4]*kb.x + qr[5]*kb.y + qr[6]*kb.z + qr[7]*kb.w;
        mx = fmaxf(mx, dot);
    }
    rmax[part][row] = mx;
    __syncthreads();
    const float Mn = fmaxf(fmaxf(rmax[0][row], rmax[1][row]), fmaxf(rmax[2][row], rmax[3][row]));

    float L = 0.f;
    float pv[8];
    for (int d = 0; d < 8; ++d) pv[d] = 0.f;
    for (int i = 0; i < 196; ++i) {
        int m = part * 196 + i;
        const float4* k4 = (const float4*)(sK + m * 8);
        float4 ka = k4[0], kb = k4[1];
        float dot = qr[0]*ka.x + qr[1]*ka.y + qr[2]*ka.z + qr[3]*ka.w
                  + qr[4]*kb.x + qr[5]*kb.y + qr[6]*kb.z + qr[7]*kb.w;
        float p = __expf(dot - Mn);
        L += p;
        const float4* v4 = (const float4*)(sV + m * 8);
        float4 va = v4[0], vb = v4[1];
        pv[0] += p * va.x; pv[1] += p * va.y; pv[2] += p * va.z; pv[3] += p * va.w;
        pv[4] += p * vb.x; pv[5] += p * vb.y; pv[6] += p * vb.z; pv[7] += p * vb.w;
    }
    rsum[part][row] = L;
    for (int d = 0; d < 8; ++d) rpv[part][row][d] = pv[d];
    __syncthreads();

    if (part == 0 && valid) {
        float Lt = rsum[0][row] + rsum[1][row] + rsum[2][row] + rsum[3][row];
        float Rr = 1.0f / Lt;
        int b = bh >> 3, h = bh & 7;
        ws[OFF_M + bh * 784 + n] = Mn;
        ws[OFF_R + bh * 784 + n] = Rr;
        float* ctx = ws + OFF_CTX + (b * 784 + n) * 64 + h * 8;
        for (int d = 0; d < 8; ++d) {
            float sv = rpv[0][row][d] + rpv[1][row][d] + rpv[2][row][d] + rpv[3][row][d];
            ctx[d] = sv * Rr;
        }
    }
}

// ---------------------------------------------------------------------------
// yo = ctx @ wproj^T + bproj + pairwise-max skip, written [B,C,H,W]
// grid (14, 8), 256 threads
// ---------------------------------------------------------------------------
__global__ __launch_bounds__(256) void k_proj(
    const float* __restrict__ x, const float* __restrict__ y,
    const float* __restrict__ wp, const float* __restrict__ bp,
    float* __restrict__ ws)
{
    __shared__ float sctx[56][68];  // padded stride
    const int tid = threadIdx.x;
    const int chunk = blockIdx.x, b = blockIdx.y;
    const int n0 = chunk * 56;
    const float* ctx = ws + OFF_CTX + (b * 784 + n0) * 64;
    for (int idx = tid; idx < 56 * 64; idx += 256) {
        int t = idx >> 6, c = idx & 63;
        sctx[t][c] = ctx[t * 64 + c];
    }
    __syncthreads();
    float* yo = ws + OFF_YO;
    for (int idx = tid; idx < 56 * 64; idx += 256) {
        int t = idx % 56, c = idx / 56;
        float acc = bp[c];
        const float4* w4 = (const float4*)(wp + c * 64);
        const float4* s4 = (const float4*)(&sctx[t][0]);
        for (int c4 = 0; c4 < 16; ++c4) {
            float4 wv = w4[c4], sv = s4[c4];
            acc += wv.x * sv.x + wv.y * sv.y + wv.z * sv.z + wv.w * sv.w;
        }
        int i = n0 + t;
        float a, b2;
        if (i < 392) {
            const float* xp = x + (b * 64 + c) * 784;
            a = xp[2 * i]; b2 = xp[2 * i + 1];
        } else {
            const float* yp = y + (b * 64 + c) * 784;
            int ii = 2 * (i - 392);
            a = yp[ii]; b2 = yp[ii + 1];
        }
        yo[(b * 64 + c) * 784 + i] = acc + fmaxf(a, b2);
    }
}

// ---------------------------------------------------------------------------
// 3x3 SAME conv, 64->64 ch on 28x28, + block-reduced BN-stat atomics
// grid (64 out-ch, 8 batch), 256 threads (196 active, 4-wide pixel quads)
// ---------------------------------------------------------------------------
__global__ __launch_bounds__(256) void k_conv_s(
    const float* __restrict__ in, const float* __restrict__ w,
    const float* __restrict__ bias, float* __restrict__ out,
    float* __restrict__ stats)
{
    const int oc = blockIdx.x, b = blockIdx.y;
    const int tid = threadIdx.x;
    float acc0 = 0.f, acc1 = 0.f, acc2 = 0.f, acc3 = 0.f;
    const int yq = tid / 7, x4 = (tid % 7) * 4;
    const bool act = tid < 196;
    if (act) {
        float bv = bias[oc];
        acc0 = acc1 = acc2 = acc3 = bv;
        const float* wbase = w + oc * 64 * 9;
        for (int ic = 0; ic < 64; ++ic) {
            const float* ip = in + (b * 64 + ic) * 784;
            const float* wic = wbase + ic * 9;
            for (int ky = 0; ky < 3; ++ky) {
                int yy = yq + ky - 1;
                if (yy < 0 || yy >= 28) continue;
                const float* rp = ip + yy * 28;
                float i0 = (x4 - 1 >= 0) ? rp[x4 - 1] : 0.0f;
                float i1 = rp[x4], i2 = rp[x4 + 1], i3 = rp[x4 + 2], i4 = rp[x4 + 3];
                float i5 = (x4 + 4 < 28) ? rp[x4 + 4] : 0.0f;
                float w0 = wic[ky * 3 + 0], w1 = wic[ky * 3 + 1], w2 = wic[ky * 3 + 2];
                acc0 += w0 * i0 + w1 * i1 + w2 * i2;
                acc1 += w0 * i1 + w1 * i2 + w2 * i3;
                acc2 += w0 * i2 + w1 * i3 + w2 * i4;
                acc3 += w0 * i3 + w1 * i4 + w2 * i5;
            }
        }
        float* op = out + (b * 64 + oc) * 784 + yq * 28 + x4;
        op[0] = acc0; op[1] = acc1; op[2] = acc2; op[3] = acc3;
    }
    float s  = acc0 + acc1 + acc2 + acc3;
    float q2 = acc0 * acc0 + acc1 * acc1 + acc2 * acc2 + acc3 * acc3;
    for (int off = 32; off >= 1; off >>= 1) {
        s  += __shfl_down(s, off);
        q2 += __shfl_down(q2, off);
    }
    __shared__ float ssum[4], ssq[4];
    const int wid = tid >> 6, lane = tid & 63;
    if (lane == 0) { ssum[wid] = s; ssq[wid] = q2; }
    __syncthreads();
    if (tid == 0) {
        atomicAdd(&stats[oc],      ssum[0] + ssum[1] + ssum[2] + ssum[3]);
        atomicAdd(&stats[64 + oc], ssq[0] + ssq[1] + ssq[2] + ssq[3]);
    }
}

// ---------------------------------------------------------------------------
// elementwise BN(training stats) + exact GELU (+ optional residual)
// ---------------------------------------------------------------------------
__global__ __launch_bounds__(256) void k_bngelu_s(
    const float* __restrict__ in, const float* __restrict__ stats,
    const float* __restrict__ gg, const float* __restrict__ bb,
    const float* __restrict__ resid, float* __restrict__ out)
{
    int idx = blockIdx.x * 256 + threadIdx.x;
    if (idx >= 8 * 64 * 784) return;
    int c = (idx / 784) & 63;
    const float cnt = 1.0f / 6272.0f;
    float m = stats[c] * cnt;
    float var = stats[64 + c] * cnt - m * m;
    float iv = rsqrtf(var + 1e-5f);
    float v = (in[idx] - m) * iv * gg[c] + bb[c];
    float ge = gelu_f(v);
    out[idx] = resid ? (ge + resid[idx]) : ge;
}

// ---------------------------------------------------------------------------
// the big one: recompute sym(attn) tile in LDS from q,k,M,R, 3x3 conv 8->8,
// write raw conv-out to d_out ctam region + BN-stat atomics.
// grid (28 tx, 28 ty, 8 b), 256 threads, 79168 B dynamic LDS
// ---------------------------------------------------------------------------
__global__ __launch_bounds__(256) void k_ctam(
    const float* __restrict__ cw, const float* __restrict__ cb,
    const float* __restrict__ ws, float* __restrict__ outc,
    float* __restrict__ statsC)
{
    extern __shared__ float smem[];
    float* qA   = smem;            // [8][30][8]
    float* kA   = smem + 1920;     // [8][30][8]
    float* qB   = smem + 3840;     // [8][30][12] padded
    float* kB   = smem + 6720;     // [8][30][12] padded
    float* MA   = smem + 9600;     // [8][30]
    float* RA   = smem + 9840;
    float* MB   = smem + 10080;
    float* RB   = smem + 10320;
    float* patch = smem + 10560;   // [8][30][36] padded
    float* wts  = smem + 19200;    // [8][3][3][8]  ([h][ky][kx][o])
    float* sred = smem + 19776;    // [8]
    float* sqred = smem + 19784;   // [8]

    const int tid = threadIdx.x;
    const int tx = blockIdx.x, ty = blockIdx.y, b = blockIdx.z;
    const int gi0 = ty * 28 - 1, gj0 = tx * 28 - 1;
    const float* qg = ws + OFF_Q;
    const float* kg = ws + OFF_K;
    const float* Mg = ws + OFF_M;
    const float* Rg = ws + OFF_R;

    for (int idx = tid; idx < 1920; idx += 256) {
        int h = idx / 240, r = (idx / 8) % 30, d = idx & 7;
        int gi = gi0 + r, gj = gj0 + r;
        bool vi = (gi >= 0 && gi < 784), vj = (gj >= 0 && gj < 784);
        int baseI = ((b * 8 + h) * 784 + gi) * 8 + d;
        int baseJ = ((b * 8 + h) * 784 + gj) * 8 + d;
        qA[(h * 30 + r) * 8 + d]  = vi ? qg[baseI] : 0.0f;
        kA[(h * 30 + r) * 8 + d]  = vi ? kg[baseI] : 0.0f;
        qB[(h * 30 + r) * 12 + d] = vj ? qg[baseJ] : 0.0f;
        kB[(h * 30 + r) * 12 + d] = vj ? kg[baseJ] : 0.0f;
    }
    for (int idx = tid; idx < 240; idx += 256) {
        int h = idx / 30, r = idx % 30;
        int gi = gi0 + r, gj = gj0 + r;
        bool vi = (gi >= 0 && gi < 784), vj = (gj >= 0 && gj < 784);
        MA[h * 30 + r] = vi ? Mg[(b * 8 + h) * 784 + gi] : 0.0f;
        RA[h * 30 + r] = vi ? Rg[(b * 8 + h) * 784 + gi] : 0.0f;
        MB[h * 30 + r] = vj ? Mg[(b * 8 + h) * 784 + gj] : 0.0f;
        RB[h * 30 + r] = vj ? Rg[(b * 8 + h) * 784 + gj] : 0.0f;
    }
    for (int idx = tid; idx < 576; idx += 256) {
        int o = idx / 72, h = (idx / 9) % 8, ky = (idx / 3) % 3, kx = idx % 3;
        wts[((h * 3 + ky) * 3 + kx) * 8 + o] = cw[((o * 8 + h) * 3 + ky) * 3 + kx];
    }
    if (tid < 8) { sred[tid] = 0.f; sqred[tid] = 0.f; }
    __syncthreads();

    // build sym(attn) patch: [8 heads][30][30] (stride 36)
    for (int e = tid; e < 7200; e += 256) {
        int h = e / 900, r = e % 900, i = r / 30, j = r % 30;
        int gi = gi0 + i, gj = gj0 + j;
        float val = 0.0f;
        if (gi >= 0 && gi < 784 && gj >= 0 && gj < 784) {
            const float4* qa = (const float4*)(qA + (h * 30 + i) * 8);
            const float4* kb = (const float4*)(kB + (h * 30 + j) * 12);
            const float4* qb = (const float4*)(qB + (h * 30 + j) * 12);
            const float4* ka = (const float4*)(kA + (h * 30 + i) * 8);
            float4 a0 = qa[0], a1 = qa[1], b0 = kb[0], b1 = kb[1];
            float d1 = a0.x*b0.x + a0.y*b0.y + a0.z*b0.z + a0.w*b0.w
                     + a1.x*b1.x + a1.y*b1.y + a1.z*b1.z + a1.w*b1.w;
            float4 c0 = qb[0], c1 = qb[1], e0 = ka[0], e1 = ka[1];
            float d2 = c0.x*e0.x + c0.y*e0.y + c0.z*e0.z + c0.w*e0.w
                     + c1.x*e1.x + c1.y*e1.y + c1.z*e1.z + c1.w*e1.w;
            val = __expf(d1 - MA[h * 30 + i]) * RA[h * 30 + i]
                + __expf(d2 - MB[h * 30 + j]) * RB[h * 30 + j];
        }
        patch[(h * 30 + i) * 36 + j] = val;
    }
    __syncthreads();

    // 3x3 conv 8ch -> 8ch on the 28x28 tile; 4-wide pixel quads
    const int iq = tid / 7, jq = (tid % 7) * 4;
    const bool act = tid < 196;
    float acc[8][4] = {};
    if (act) {
        #pragma unroll
        for (int o = 0; o < 8; ++o) {
            float bv = cb[o];
            acc[o][0] = bv; acc[o][1] = bv; acc[o][2] = bv; acc[o][3] = bv;
        }
        for (int h = 0; h < 8; ++h) {
            #pragma unroll
            for (int ky = 0; ky < 3; ++ky) {
                const float* prow = patch + (h * 30 + iq + ky) * 36 + jq;
                float rr[6];
                rr[0] = prow[0]; rr[1] = prow[1]; rr[2] = prow[2];
                rr[3] = prow[3]; rr[4] = prow[4]; rr[5] = prow[5];
                #pragma unroll
                for (int kx = 0; kx < 3; ++kx) {
                    const float4* wv = (const float4*)(wts + ((h * 3 + ky) * 3 + kx) * 8);
                    float4 w0 = wv[0], w1 = wv[1];
                    float s0 = rr[kx], s1 = rr[kx + 1], s2 = rr[kx + 2], s3 = rr[kx + 3];
#define ACC4(o, wv_) acc[o][0] += wv_ * s0; acc[o][1] += wv_ * s1; acc[o][2] += wv_ * s2; acc[o][3] += wv_ * s3;
                    ACC4(0, w0.x) ACC4(1, w0.y) ACC4(2, w0.z) ACC4(3, w0.w)
                    ACC4(4, w1.x) ACC4(5, w1.y) ACC4(6, w1.z) ACC4(7, w1.w)
#undef ACC4
                }
            }
        }
        const int go = ty * 28 + iq;
        const int gj = tx * 28 + jq;
        #pragma unroll
        for (int o = 0; o < 8; ++o) {
            float4 st = make_float4(acc[o][0], acc[o][1], acc[o][2], acc[o][3]);
            float* dst = outc + (size_t)(b * 8 + o) * 614656 + go * 784 + gj;
            *(float4*)dst = st;
        }
    }

    // BN-stat reduction: wave shuffles -> LDS atomics -> global atomics
    #pragma unroll
    for (int o = 0; o < 8; ++o) {
        float a  = acc[o][0] + acc[o][1] + acc[o][2] + acc[o][3];
        float q2 = acc[o][0] * acc[o][0] + acc[o][1] * acc[o][1]
                 + acc[o][2] * acc[o][2] + acc[o][3] * acc[o][3];
        for (int off = 32; off >= 1; off >>= 1) {
            a  += __shfl_down(a, off);
            q2 += __shfl_down(q2, off);
        }
        if ((tid & 63) == 0) { atomicAdd(&sred[o], a); atomicAdd(&sqred[o], q2); }
    }
    __syncthreads();
    if (tid < 8) {
        atomicAdd(&statsC[tid], sred[tid]);
        atomicAdd(&statsC[8 + tid], sqred[tid]);
    }
}

// ---------------------------------------------------------------------------
// in-place BN + GELU over the 39.3M-element ctam region (float4 grid-stride)
// ---------------------------------------------------------------------------
__global__ __launch_bounds__(256) void k_bnc(
    float* __restrict__ data, const float* __restrict__ stats,
    const float* __restrict__ gg, const float* __restrict__ bb)
{
    const float cnt = 1.0f / 4917248.0f;  // B*N*N
    long idx4 = (long)blockIdx.x * 256 + threadIdx.x;
    const long stride = (long)gridDim.x * 256;
    const long total4 = 39337984L / 4;
    for (; idx4 < total4; idx4 += stride) {
        long e = idx4 * 4;
        int o = (int)((e / 614656) & 7);
        float m = stats[o] * cnt;
        float var = stats[8 + o] * cnt - m * m;
        float iv = rsqrtf(var + 1e-5f);
        float sc = gg[o] * iv, sh = bb[o] - m * sc;
        float4 v = ((float4*)data)[idx4];
        v.x = gelu_f(v.x * sc + sh);
        v.y = gelu_f(v.y * sc + sh);
        v.z = gelu_f(v.z * sc + sh);
        v.w = gelu_f(v.w * sc + sh);
        ((float4*)data)[idx4] = v;
    }
}

// ---------------------------------------------------------------------------
extern "C" void kernel_launch(void* const* d_in, const int* in_sizes, int n_in,
                              void* d_out, int out_size, void* d_ws, size_t ws_size,
                              hipStream_t stream) {
    (void)in_sizes; (void)n_in; (void)out_size; (void)ws_size;
    const float* x      = (const float*)d_in[0];
    const float* y      = (const float*)d_in[1];
    const float* lnx_w  = (const float*)d_in[2];
    const float* lnx_b  = (const float*)d_in[3];
    const float* lny_w  = (const float*)d_in[4];
    const float* lny_b  = (const float*)d_in[5];
    const float* wqkvr  = (const float*)d_in[6];
    const float* bqkvr  = (const float*)d_in[7];
    const float* wqkvs  = (const float*)d_in[8];
    const float* bqkvs  = (const float*)d_in[9];
    const float* wproj  = (const float*)d_in[10];
    const float* bproj  = (const float*)d_in[11];
    const float* conv_w = (const float*)d_in[12];
    const float* conv_b = (const float*)d_in[13];
    const float* bn_g   = (const float*)d_in[14];
    const float* bn_b   = (const float*)d_in[15];
    const float* c2w1   = (const float*)d_in[16];
    const float* c2b1   = (const float*)d_in[17];
    const float* bn1_g  = (const float*)d_in[18];
    const float* bn1_b  = (const float*)d_in[19];
    const float* c2w2   = (const float*)d_in[20];
    const float* c2b2   = (const float*)d_in[21];
    const float* bn2_g  = (const float*)d_in[22];
    const float* bn2_b  = (const float*)d_in[23];
    float* out = (float*)d_out;
    float* ws  = (float*)d_ws;

    hipMemsetAsync(ws, 0, 512 * sizeof(float), stream);
    k_qkv<<<dim3(14, 8), 256, 0, stream>>>(x, y, lnx_w, lnx_b, lny_w, lny_b,
                                           wqkvr, bqkvr, wqkvs, bqkvs, ws);
    k_flash<<<dim3(13, 64), 256, 0, stream>>>(ws);
    k_proj<<<dim3(14, 8), 256, 0, stream>>>(x, y, wproj, bproj, ws);
    k_conv_s<<<dim3(64, 8), 256, 0, stream>>>(ws + OFF_YO, c2w1, c2b1,
                                              ws + OFF_H1, ws + OFF_STATS);
    k_bngelu_s<<<1568, 256, 0, stream>>>(ws + OFF_H1, ws + OFF_STATS,
                                         bn1_g, bn1_b, nullptr, ws + OFF_G1);
    k_conv_s<<<dim3(64, 8), 256, 0, stream>>>(ws + OFF_G1, c2w2, c2b2,
                                              ws + OFF_H2, ws + OFF_STATS + 128);
    k_bngelu_s<<<1568, 256, 0, stream>>>(ws + OFF_H2, ws + OFF_STATS + 128,
                                         bn2_g, bn2_b, ws + OFF_YO, out);
    k_ctam<<<dim3(28, 28, 8), 256, 19792 * sizeof(float), stream>>>(
        conv_w, conv_b, ws, out + 401408, ws + OFF_STATS + 256);
    k_bnc<<<4096, 256, 0, stream>>>(out + 401408, ws + OFF_STATS + 256, bn_g, bn_b);
}

// Round 3
// 575.171 us; speedup vs baseline: 1.1831x; 1.1831x over previous
//
#include <hip/hip_runtime.h>
#include <math.h>

#define SCALE 0.35355339059327373f  // 1/sqrt(8)

// workspace float offsets
#define OFF_STATS 0              // [0..63] bn1 sum, [64..127] bn1 sq, [128..191] bn2 sum,
                                 // [192..255] bn2 sq, [256..263] bnc sum, [264..271] bnc sq
#define OFF_Q   512
#define OFF_K   (OFF_Q + 401408)
#define OFF_V   (OFF_K + 401408)
#define OFF_M   (OFF_V + 401408)
#define OFF_R   (OFF_M + 50176)
#define OFF_CTX (OFF_R + 50176)
#define OFF_YO  (OFF_CTX + 401408)
#define OFF_H1  (OFF_YO + 401408)
#define OFF_G1  (OFF_H1 + 401408)
#define OFF_H2  (OFF_G1 + 401408)

__device__ __forceinline__ float gelu_f(float v) {
    return 0.5f * v * (1.0f + erff(v * 0.70710678118654752f));
}

// ---------------------------------------------------------------------------
// LN(x), LN(y) + fused QKV projections (q scaled by 1/sqrt(hd) at write)
// grid (49 chunks of 16 tokens, 8 batches), 256 threads
// ---------------------------------------------------------------------------
__global__ __launch_bounds__(256) void k_qkv(
    const float* __restrict__ x, const float* __restrict__ y,
    const float* __restrict__ lnxw, const float* __restrict__ lnxb,
    const float* __restrict__ lnyw, const float* __restrict__ lnyb,
    const float* __restrict__ wr, const float* __restrict__ br,
    const float* __restrict__ wsw, const float* __restrict__ bs,
    float* __restrict__ ws)
{
    __shared__ float snx[16][68];
    __shared__ float sny[16][68];
    const int tid = threadIdx.x;
    const int chunk = blockIdx.x, b = blockIdx.y;
    const int n0 = chunk * 16;
    const int t = tid >> 4;      // token 0..15
    const int l = tid & 15;      // 16 lanes per token, 4 channels each

    // LN for x and y: each lane owns channels 4l..4l+3 of token t
    for (int which = 0; which < 2; ++which) {
        const float* src = which ? y : x;
        const float* w   = which ? lnyw : lnxw;
        const float* bb  = which ? lnyb : lnxb;
        float v0 = src[(b * 64 + 4 * l + 0) * 784 + n0 + t];
        float v1 = src[(b * 64 + 4 * l + 1) * 784 + n0 + t];
        float v2 = src[(b * 64 + 4 * l + 2) * 784 + n0 + t];
        float v3 = src[(b * 64 + 4 * l + 3) * 784 + n0 + t];
        float s = v0 + v1 + v2 + v3;
        float q = v0 * v0 + v1 * v1 + v2 * v2 + v3 * v3;
        for (int off = 1; off < 16; off <<= 1) {
            s += __shfl_xor(s, off);
            q += __shfl_xor(q, off);
        }
        float m  = s * (1.0f / 64.0f);
        float iv = rsqrtf(q * (1.0f / 64.0f) - m * m + 1e-5f);
        float* dst = which ? &sny[t][0] : &snx[t][0];
        dst[4 * l + 0] = (v0 - m) * iv * w[4 * l + 0] + bb[4 * l + 0];
        dst[4 * l + 1] = (v1 - m) * iv * w[4 * l + 1] + bb[4 * l + 1];
        dst[4 * l + 2] = (v2 - m) * iv * w[4 * l + 2] + bb[4 * l + 2];
        dst[4 * l + 3] = (v3 - m) * iv * w[4 * l + 3] + bb[4 * l + 3];
    }
    __syncthreads();

    float* qout = ws + OFF_Q;
    float* kout = ws + OFF_K;
    float* vout = ws + OFF_V;
    for (int idx = tid; idx < 16 * 192; idx += 256) {
        int tt = idx & 15, o = idx >> 4;
        float acc = br[o] + bs[o];
        const float4* wro = (const float4*)(wr + o * 64);
        const float4* wso = (const float4*)(wsw + o * 64);
        const float4* sx4 = (const float4*)(&snx[tt][0]);
        const float4* sy4 = (const float4*)(&sny[tt][0]);
        #pragma unroll 4
        for (int c4 = 0; c4 < 16; ++c4) {
            float4 a = sx4[c4], wa = wro[c4];
            float4 c = sy4[c4], wc = wso[c4];
            acc += a.x * wa.x + a.y * wa.y + a.z * wa.z + a.w * wa.w
                 + c.x * wc.x + c.y * wc.y + c.z * wc.z + c.w * wc.w;
        }
        int s = o >> 6, h = (o >> 3) & 7, d = o & 7;
        int n = n0 + tt;
        float* dst = (s == 0) ? qout : (s == 1 ? kout : vout);
        if (s == 0) acc *= SCALE;
        dst[((b * 8 + h) * 784 + n) * 8 + d] = acc;
    }
}

// ---------------------------------------------------------------------------
// flash pass: per-row softmax stats (M, R=1/L) and ctx = softmax(qk^T) v
// grid (13 row-chunks of 64, 64 bh), 256 threads: lane=row, wave=m-partition
// K/V rows read directly from global: wave-uniform address -> L1 broadcast
// ---------------------------------------------------------------------------
__global__ __launch_bounds__(256) void k_flash(float* __restrict__ ws)
{
    __shared__ float rmax[4][64];
    __shared__ float rsum[4][64];
    __shared__ float rpv[4][64][8];
    const int tid = threadIdx.x;
    const int chunk = blockIdx.x;   // 0..12
    const int bh = blockIdx.y;      // 0..63
    const float* q = ws + OFF_Q + bh * 784 * 8;
    const float* k = ws + OFF_K + bh * 784 * 8;
    const float* v = ws + OFF_V + bh * 784 * 8;

    const int row = tid & 63, part = tid >> 6;
    const int n = chunk * 64 + row;
    const bool valid = n < 784;
    float qr[8];
    if (valid) {
        const float4* q4 = (const float4*)(q + n * 8);
        float4 a = q4[0], bq = q4[1];
        qr[0] = a.x; qr[1] = a.y; qr[2] = a.z; qr[3] = a.w;
        qr[4] = bq.x; qr[5] = bq.y; qr[6] = bq.z; qr[7] = bq.w;
    } else {
        for (int d = 0; d < 8; ++d) qr[d] = 0.f;
    }

    float mx = -1e30f;
    for (int i = 0; i < 196; ++i) {
        int m = part * 196 + i;
        const float4* k4 = (const float4*)(k + m * 8);
        float4 ka = k4[0], kb = k4[1];
        float dot = qr[0]*ka.x + qr[1]*ka.y + qr[2]*ka.z + qr[3]*ka.w
                  + qr[4]*kb.x + qr[5]*kb.y + qr[6]*kb.z + qr[7]*kb.w;
        mx = fmaxf(mx, dot);
    }
    rmax[part][row] = mx;
    __syncthreads();
    const float Mn = fmaxf(fmaxf(rmax[0][row], rmax[1][row]), fmaxf(rmax[2][row], rmax[3][row]));

    float L = 0.f;
    float pv[8];
    for (int d = 0; d < 8; ++d) pv[d] = 0.f;
    for (int i = 0; i < 196; ++i) {
        int m = part * 196 + i;
        const float4* k4 = (const float4*)(k + m * 8);
        float4 ka = k4[0], kb = k4[1];
        float dot = qr[0]*ka.x + qr[1]*ka.y + qr[2]*ka.z + qr[3]*ka.w
                  + qr[4]*kb.x + qr[5]*kb.y + qr[6]*kb.z + qr[7]*kb.w;
        float p = __expf(dot - Mn);
        L += p;
        const float4* v4 = (const float4*)(v + m * 8);
        float4 va = v4[0], vb = v4[1];
        pv[0] += p * va.x; pv[1] += p * va.y; pv[2] += p * va.z; pv[3] += p * va.w;
        pv[4] += p * vb.x; pv[5] += p * vb.y; pv[6] += p * vb.z; pv[7] += p * vb.w;
    }
    rsum[part][row] = L;
    for (int d = 0; d < 8; ++d) rpv[part][row][d] = pv[d];
    __syncthreads();

    if (part == 0 && valid) {
        float Lt = rsum[0][row] + rsum[1][row] + rsum[2][row] + rsum[3][row];
        float Rr = 1.0f / Lt;
        int b = bh >> 3, h = bh & 7;
        ws[OFF_M + bh * 784 + n] = Mn;
        ws[OFF_R + bh * 784 + n] = Rr;
        float* ctx = ws + OFF_CTX + (b * 784 + n) * 64 + h * 8;
        for (int d = 0; d < 8; ++d) {
            float sv = rpv[0][row][d] + rpv[1][row][d] + rpv[2][row][d] + rpv[3][row][d];
            ctx[d] = sv * Rr;
        }
    }
}

// ---------------------------------------------------------------------------
// yo = ctx @ wproj^T + bproj + pairwise-max skip, written [B,C,H,W]
// grid (28, 8), 256 threads
// ---------------------------------------------------------------------------
__global__ __launch_bounds__(256) void k_proj(
    const float* __restrict__ x, const float* __restrict__ y,
    const float* __restrict__ wp, const float* __restrict__ bp,
    float* __restrict__ ws)
{
    __shared__ float sctx[28][68];  // padded stride
    const int tid = threadIdx.x;
    const int chunk = blockIdx.x, b = blockIdx.y;
    const int n0 = chunk * 28;
    const float* ctx = ws + OFF_CTX + (b * 784 + n0) * 64;
    for (int idx = tid; idx < 28 * 64; idx += 256) {
        int t = idx >> 6, c = idx & 63;
        sctx[t][c] = ctx[t * 64 + c];
    }
    __syncthreads();
    float* yo = ws + OFF_YO;
    for (int idx = tid; idx < 28 * 64; idx += 256) {
        int t = idx % 28, c = idx / 28;
        float acc = bp[c];
        const float4* w4 = (const float4*)(wp + c * 64);
        const float4* s4 = (const float4*)(&sctx[t][0]);
        for (int c4 = 0; c4 < 16; ++c4) {
            float4 wv = w4[c4], sv = s4[c4];
            acc += wv.x * sv.x + wv.y * sv.y + wv.z * sv.z + wv.w * sv.w;
        }
        int i = n0 + t;
        float a, b2;
        if (i < 392) {
            const float* xp = x + (b * 64 + c) * 784;
            a = xp[2 * i]; b2 = xp[2 * i + 1];
        } else {
            const float* yp = y + (b * 64 + c) * 784;
            int ii = 2 * (i - 392);
            a = yp[ii]; b2 = yp[ii + 1];
        }
        yo[(b * 64 + c) * 784 + i] = acc + fmaxf(a, b2);
    }
}

// ---------------------------------------------------------------------------
// 3x3 SAME conv, 64->64 ch on 28x28, + block-reduced BN-stat atomics
// grid (64 out-ch, 8 batch, 2 row-halves), 128 threads (98 active)
// ---------------------------------------------------------------------------
__global__ __launch_bounds__(128) void k_conv_s(
    const float* __restrict__ in, const float* __restrict__ w,
    const float* __restrict__ bias, float* __restrict__ out,
    float* __restrict__ stats)
{
    const int oc = blockIdx.x, b = blockIdx.y, half = blockIdx.z;
    const int tid = threadIdx.x;
    float acc0 = 0.f, acc1 = 0.f, acc2 = 0.f, acc3 = 0.f;
    const int yq = half * 14 + tid / 7, x4 = (tid % 7) * 4;
    const bool act = tid < 98;
    if (act) {
        float bv = bias[oc];
        acc0 = acc1 = acc2 = acc3 = bv;
        const float* wbase = w + oc * 64 * 9;
        for (int ic = 0; ic < 64; ++ic) {
            const float* ip = in + (b * 64 + ic) * 784;
            const float* wic = wbase + ic * 9;
            #pragma unroll
            for (int ky = 0; ky < 3; ++ky) {
                int yy = yq + ky - 1;
                if (yy < 0 || yy >= 28) continue;
                const float* rp = ip + yy * 28 + x4;
                float4 mid = *(const float4*)rp;
                float i0 = (x4 > 0) ? rp[-1] : 0.0f;
                float i5 = (x4 < 24) ? rp[4] : 0.0f;
                float w0 = wic[ky * 3 + 0], w1 = wic[ky * 3 + 1], w2 = wic[ky * 3 + 2];
                acc0 += w0 * i0    + w1 * mid.x + w2 * mid.y;
                acc1 += w0 * mid.x + w1 * mid.y + w2 * mid.z;
                acc2 += w0 * mid.y + w1 * mid.z + w2 * mid.w;
                acc3 += w0 * mid.z + w1 * mid.w + w2 * i5;
            }
        }
        float* op = out + (b * 64 + oc) * 784 + yq * 28 + x4;
        op[0] = acc0; op[1] = acc1; op[2] = acc2; op[3] = acc3;
    }
    float s  = acc0 + acc1 + acc2 + acc3;
    float q2 = acc0 * acc0 + acc1 * acc1 + acc2 * acc2 + acc3 * acc3;
    for (int off = 32; off >= 1; off >>= 1) {
        s  += __shfl_down(s, off);
        q2 += __shfl_down(q2, off);
    }
    __shared__ float ssum[2], ssq[2];
    const int wid = tid >> 6, lane = tid & 63;
    if (lane == 0) { ssum[wid] = s; ssq[wid] = q2; }
    __syncthreads();
    if (tid == 0) {
        atomicAdd(&stats[oc],      ssum[0] + ssum[1]);
        atomicAdd(&stats[64 + oc], ssq[0] + ssq[1]);
    }
}

// ---------------------------------------------------------------------------
// elementwise BN(training stats) + exact GELU (+ optional residual)
// ---------------------------------------------------------------------------
__global__ __launch_bounds__(256) void k_bngelu_s(
    const float* __restrict__ in, const float* __restrict__ stats,
    const float* __restrict__ gg, const float* __restrict__ bb,
    const float* __restrict__ resid, float* __restrict__ out)
{
    int idx = blockIdx.x * 256 + threadIdx.x;
    if (idx >= 8 * 64 * 784) return;
    int c = (idx / 784) & 63;
    const float cnt = 1.0f / 6272.0f;
    float m = stats[c] * cnt;
    float var = stats[64 + c] * cnt - m * m;
    float iv = rsqrtf(var + 1e-5f);
    float v = (in[idx] - m) * iv * gg[c] + bb[c];
    float ge = gelu_f(v);
    out[idx] = resid ? (ge + resid[idx]) : ge;
}

// ---------------------------------------------------------------------------
// sym(attn) recompute + 3x3 conv 8->8, phased over 4 head-pairs.
// i-side (q,k,M,R) in registers; j-side rows + patch in LDS (~15 KB).
// grid (28 tx, 28 ty, 8 b), 256 threads
// ---------------------------------------------------------------------------
__global__ __launch_bounds__(256, 4) void k_ctam(
    const float* __restrict__ cw, const float* __restrict__ cb,
    const float* __restrict__ ws, float* __restrict__ outc,
    float* __restrict__ statsC)
{
    __shared__ float kB[540];       // [2][30][9]
    __shared__ float qB[540];
    __shared__ float MB[60], RB[60];
    __shared__ float patch[1980];   // [2][30][33]
    __shared__ float wts[576];      // [h][ky][kx][o]
    __shared__ float sred[8], sqred[8];

    const int tid = threadIdx.x;
    const int tx = blockIdx.x, ty = blockIdx.y, b = blockIdx.z;
    const int gi0 = ty * 28 - 1, gj0 = tx * 28 - 1;
    const float* qg = ws + OFF_Q;
    const float* kg = ws + OFF_K;
    const float* Mg = ws + OFF_M;
    const float* Rg = ws + OFF_R;

    for (int idx = tid; idx < 576; idx += 256) {
        int o = idx / 72, h = (idx / 9) % 8, ky = (idx / 3) % 3, kx = idx % 3;
        wts[((h * 3 + ky) * 3 + kx) * 8 + o] = cw[((o * 8 + h) * 3 + ky) * 3 + kx];
    }
    if (tid < 8) { sred[tid] = 0.f; sqred[tid] = 0.f; }

    // build-phase lane roles: (h2, row i, j-quarter)
    const int h2 = tid / 120;            // 0,1 for tid<240
    const int li = (tid % 120) >> 2;     // 0..29
    const int jq = tid & 3;              // 0..3
    const bool bact = tid < 240;
    const int gi = gi0 + li;
    const bool vi = bact && gi >= 0 && gi < 784;

    // conv-phase lane roles
    const int iq = tid / 7, jq4 = (tid % 7) * 4;
    const bool cact = tid < 196;

    float acc[8][4];
    #pragma unroll
    for (int o = 0; o < 8; ++o) {
        float bv = cact ? cb[o] : 0.0f;
        acc[o][0] = bv; acc[o][1] = bv; acc[o][2] = bv; acc[o][3] = bv;
    }

    for (int p = 0; p < 4; ++p) {
        __syncthreads();   // prev conv done reading patch / prev build done reading kB,qB
        // j-side rows -> LDS (heads 2p, 2p+1)
        for (int idx = tid; idx < 480; idx += 256) {
            int hh = idx / 240, r = (idx >> 3) % 30, d = idx & 7;
            int gj = gj0 + r;
            bool vj = (gj >= 0 && gj < 784);
            int base = ((b * 8 + 2 * p + hh) * 784 + gj) * 8 + d;
            kB[(hh * 30 + r) * 9 + d] = vj ? kg[base] : 0.0f;
            qB[(hh * 30 + r) * 9 + d] = vj ? qg[base] : 0.0f;
        }
        for (int idx = tid; idx < 60; idx += 256) {
            int hh = idx / 30, r = idx % 30;
            int gj = gj0 + r;
            bool vj = (gj >= 0 && gj < 784);
            int base = (b * 8 + 2 * p + hh) * 784 + gj;
            MB[idx] = vj ? Mg[base] : 0.0f;
            RB[idx] = vj ? Rg[base] : 0.0f;
        }
        // i-side into registers
        float qa[8], ka[8], Ma = 0.f, Ra = 0.f;
        if (vi) {
            int base = ((b * 8 + 2 * p + h2) * 784 + gi) * 8;
            const float4* q4 = (const float4*)(qg + base);
            const float4* k4 = (const float4*)(kg + base);
            float4 a0 = q4[0], a1 = q4[1], b0 = k4[0], b1 = k4[1];
            qa[0]=a0.x; qa[1]=a0.y; qa[2]=a0.z; qa[3]=a0.w;
            qa[4]=a1.x; qa[5]=a1.y; qa[6]=a1.z; qa[7]=a1.w;
            ka[0]=b0.x; ka[1]=b0.y; ka[2]=b0.z; ka[3]=b0.w;
            ka[4]=b1.x; ka[5]=b1.y; ka[6]=b1.z; ka[7]=b1.w;
            Ma = Mg[(b * 8 + 2 * p + h2) * 784 + gi];
            Ra = Rg[(b * 8 + 2 * p + h2) * 784 + gi];
        } else {
            #pragma unroll
            for (int d = 0; d < 8; ++d) { qa[d] = 0.f; ka[d] = 0.f; }
        }
        __syncthreads();
        // build patch rows for this head-pair
        if (bact) {
            #pragma unroll 2
            for (int s = 0; s < 8; ++s) {
                int j = jq * 8 + s;
                if (j < 30) {
                    int gj = gj0 + j;
                    float val = 0.0f;
                    if (vi && gj >= 0 && gj < 784) {
                        const float* kb = kB + (h2 * 30 + j) * 9;
                        const float* qb = qB + (h2 * 30 + j) * 9;
                        float d1 = qa[0]*kb[0] + qa[1]*kb[1] + qa[2]*kb[2] + qa[3]*kb[3]
                                 + qa[4]*kb[4] + qa[5]*kb[5] + qa[6]*kb[6] + qa[7]*kb[7];
                        float d2 = ka[0]*qb[0] + ka[1]*qb[1] + ka[2]*qb[2] + ka[3]*qb[3]
                                 + ka[4]*qb[4] + ka[5]*qb[5] + ka[6]*qb[6] + ka[7]*qb[7];
                        val = __expf(d1 - Ma) * Ra
                            + __expf(d2 - MB[h2 * 30 + j]) * RB[h2 * 30 + j];
                    }
                    patch[(h2 * 30 + li) * 33 + j] = val;
                }
            }
        }
        __syncthreads();
        // conv-accumulate this head-pair
        if (cact) {
            #pragma unroll
            for (int hh = 0; hh < 2; ++hh) {
                int h = 2 * p + hh;
                #pragma unroll
                for (int ky = 0; ky < 3; ++ky) {
                    const float* prow = patch + (hh * 30 + iq + ky) * 33 + jq4;
                    float rr[6];
                    rr[0] = prow[0]; rr[1] = prow[1]; rr[2] = prow[2];
                    rr[3] = prow[3]; rr[4] = prow[4]; rr[5] = prow[5];
                    #pragma unroll
                    for (int kx = 0; kx < 3; ++kx) {
                        const float4* wv = (const float4*)(wts + ((h * 3 + ky) * 3 + kx) * 8);
                        float4 w0 = wv[0], w1 = wv[1];
                        float s0 = rr[kx], s1 = rr[kx + 1], s2 = rr[kx + 2], s3 = rr[kx + 3];
#define ACC4(o, wv_) acc[o][0] += wv_ * s0; acc[o][1] += wv_ * s1; acc[o][2] += wv_ * s2; acc[o][3] += wv_ * s3;
                        ACC4(0, w0.x) ACC4(1, w0.y) ACC4(2, w0.z) ACC4(3, w0.w)
                        ACC4(4, w1.x) ACC4(5, w1.y) ACC4(6, w1.z) ACC4(7, w1.w)
#undef ACC4
                    }
                }
            }
        }
    }

    if (cact) {
        const int go = ty * 28 + iq;
        const int gj = tx * 28 + jq4;
        #pragma unroll
        for (int o = 0; o < 8; ++o) {
            float4 st = make_float4(acc[o][0], acc[o][1], acc[o][2], acc[o][3]);
            float* dst = outc + (size_t)(b * 8 + o) * 614656 + go * 784 + gj;
            *(float4*)dst = st;
        }
    }

    #pragma unroll
    for (int o = 0; o < 8; ++o) {
        float a  = acc[o][0] + acc[o][1] + acc[o][2] + acc[o][3];
        float q2 = acc[o][0] * acc[o][0] + acc[o][1] * acc[o][1]
                 + acc[o][2] * acc[o][2] + acc[o][3] * acc[o][3];
        for (int off = 32; off >= 1; off >>= 1) {
            a  += __shfl_down(a, off);
            q2 += __shfl_down(q2, off);
        }
        if ((tid & 63) == 0) { atomicAdd(&sred[o], a); atomicAdd(&sqred[o], q2); }
    }
    __syncthreads();
    if (tid < 8) {
        atomicAdd(&statsC[tid], sred[tid]);
        atomicAdd(&statsC[8 + tid], sqred[tid]);
    }
}

// ---------------------------------------------------------------------------
// in-place BN + GELU over the ctam region; blockIdx.y = plane (b*8+o), 64 total
// ---------------------------------------------------------------------------
__global__ __launch_bounds__(256) void k_bnc(
    float* __restrict__ data, const float* __restrict__ stats,
    const float* __restrict__ gg, const float* __restrict__ bb)
{
    const int plane = blockIdx.y;      // b*8 + o, 0..63
    const int o = plane & 7;           // channel
    const float cnt = 1.0f / 4917248.0f;  // B*N*N
    float m = stats[o] * cnt;
    float var = stats[8 + o] * cnt - m * m;
    float iv = rsqrtf(var + 1e-5f);
    float sc = gg[o] * iv, sh = bb[o] - m * sc;
    int i4 = blockIdx.x * 256 + threadIdx.x;
    if (i4 < 153664) {  // 614656/4
        float4* dp = (float4*)(data + (size_t)plane * 614656);
        float4 v = dp[i4];
        v.x = gelu_f(v.x * sc + sh);
        v.y = gelu_f(v.y * sc + sh);
        v.z = gelu_f(v.z * sc + sh);
        v.w = gelu_f(v.w * sc + sh);
        dp[i4] = v;
    }
}

// ---------------------------------------------------------------------------
extern "C" void kernel_launch(void* const* d_in, const int* in_sizes, int n_in,
                              void* d_out, int out_size, void* d_ws, size_t ws_size,
                              hipStream_t stream) {
    (void)in_sizes; (void)n_in; (void)out_size; (void)ws_size;
    const float* x      = (const float*)d_in[0];
    const float* y      = (const float*)d_in[1];
    const float* lnx_w  = (const float*)d_in[2];
    const float* lnx_b  = (const float*)d_in[3];
    const float* lny_w  = (const float*)d_in[4];
    const float* lny_b  = (const float*)d_in[5];
    const float* wqkvr  = (const float*)d_in[6];
    const float* bqkvr  = (const float*)d_in[7];
    const float* wqkvs  = (const float*)d_in[8];
    const float* bqkvs  = (const float*)d_in[9];
    const float* wproj  = (const float*)d_in[10];
    const float* bproj  = (const float*)d_in[11];
    const float* conv_w = (const float*)d_in[12];
    const float* conv_b = (const float*)d_in[13];
    const float* bn_g   = (const float*)d_in[14];
    const float* bn_b   = (const float*)d_in[15];
    const float* c2w1   = (const float*)d_in[16];
    const float* c2b1   = (const float*)d_in[17];
    const float* bn1_g  = (const float*)d_in[18];
    const float* bn1_b  = (const float*)d_in[19];
    const float* c2w2   = (const float*)d_in[20];
    const float* c2b2   = (const float*)d_in[21];
    const float* bn2_g  = (const float*)d_in[22];
    const float* bn2_b  = (const float*)d_in[23];
    float* out = (float*)d_out;
    float* ws  = (float*)d_ws;

    hipMemsetAsync(ws, 0, 512 * sizeof(float), stream);
    k_qkv<<<dim3(49, 8), 256, 0, stream>>>(x, y, lnx_w, lnx_b, lny_w, lny_b,
                                           wqkvr, bqkvr, wqkvs, bqkvs, ws);
    k_flash<<<dim3(13, 64), 256, 0, stream>>>(ws);
    k_proj<<<dim3(28, 8), 256, 0, stream>>>(x, y, wproj, bproj, ws);
    k_conv_s<<<dim3(64, 8, 2), 128, 0, stream>>>(ws + OFF_YO, c2w1, c2b1,
                                                 ws + OFF_H1, ws + OFF_STATS);
    k_bngelu_s<<<1568, 256, 0, stream>>>(ws + OFF_H1, ws + OFF_STATS,
                                         bn1_g, bn1_b, nullptr, ws + OFF_G1);
    k_conv_s<<<dim3(64, 8, 2), 128, 0, stream>>>(ws + OFF_G1, c2w2, c2b2,
                                                 ws + OFF_H2, ws + OFF_STATS + 128);
    k_bngelu_s<<<1568, 256, 0, stream>>>(ws + OFF_H2, ws + OFF_STATS + 128,
                                         bn2_g, bn2_b, ws + OFF_YO, out);
    k_ctam<<<dim3(28, 28, 8), 256, 0, stream>>>(
        conv_w, conv_b, ws, out + 401408, ws + OFF_STATS + 256);
    k_bnc<<<dim3(601, 64), 256, 0, stream>>>(out + 401408, ws + OFF_STATS + 256, bn_g, bn_b);
}